// Round 3
// baseline (1091.709 us; speedup 1.0000x reference)
//
#include <hip/hip_runtime.h>
#include <hip/hip_bf16.h>
#include <math.h>

#define N 1026
#define T 8
#define H 64
#define F_IN 5
#define E 1026
#define NNZ 200000
#define TM 7
#define NG 9
#define SE 1056
#define NW (SE/4)
#define GSZ (N*SE)
#define KP 1056        // padded K (rows of padded X buffers)
#define MT 32          // GEMM rows per block
#define KT 96          // GEMM k-tile (96*11 = 1056 exactly)
#define KSTEPS 11

#define OFF_PRICE   0
#define OFF_WIH     41040
#define OFF_WHH     42000
#define OFF_BIH     54288
#define OFF_BHH     54480
#define OFF_WIN     54672
#define OFF_WOUT    58768
#define OFF_AE      66960
#define OFF_AB      67986
#define OFF_TH1     69012
#define OFF_B1      73108
#define OFF_TH2     73172
#define OFF_B2      77268
#define OFF_W1      77332
#define OFF_W2      77780
#define OFF_APAR    78228
#define OFF_WL      78235
#define OFF_BL      78363
#define TOT_CVT     78364
#define CVT_PAD     78368

typedef unsigned int u32;

__device__ __forceinline__ float leakyf(float x){ return x >= 0.f ? x : 0.2f*x; }
__device__ __forceinline__ float bfbits2f(unsigned short u){
  union { unsigned int i; float f; } c; c.i = ((unsigned int)u) << 16; return c.f;
}

__global__ __launch_bounds__(64) void k_detect(const unsigned short* __restrict__ w,
                                               int* __restrict__ flag){
  int tid = threadIdx.x;
  int big = 0;
  for (int k = tid; k < 960; k += 64){
    float a = fabsf(bfbits2f(w[k]));
    if (!(a < 1e3f)) big = 1;
  }
  unsigned long long any = __ballot(big != 0);
  if (tid == 0) *flag = (any != 0ull) ? 1 : 0;
}

struct CvtPtrs { const void* p[18]; };

__global__ __launch_bounds__(256) void k_cvt(const int* __restrict__ flag,
                                             CvtPtrs ps, float* __restrict__ dst){
  const int offs[19] = {OFF_PRICE, OFF_WIH, OFF_WHH, OFF_BIH, OFF_BHH, OFF_WIN,
                        OFF_WOUT, OFF_AE, OFF_AB, OFF_TH1, OFF_B1, OFF_TH2,
                        OFF_B2, OFF_W1, OFF_W2, OFF_APAR, OFF_WL, OFF_BL, TOT_CVT};
  int i = blockIdx.x*256 + threadIdx.x;
  if (i >= TOT_CVT) return;
  int t = 0;
  #pragma unroll
  for (int k = 1; k < 18; k++) if (i >= offs[k]) t = k;
  int j = i - offs[t];
  float v;
  if (*flag) v = ((const float*)ps.p[t])[j];
  else       v = bfbits2f(((const unsigned short*)ps.p[t])[j]);
  dst[i] = v;
}

__global__ __launch_bounds__(256) void k_build(const int* __restrict__ hypT,
                                               const int* __restrict__ hyp,
                                               u32* __restrict__ cHm,
                                               u32* __restrict__ cHmT){
  int g = blockIdx.y;
  int i = blockIdx.x*256 + threadIdx.x;
  if (i >= NNZ) return;
  const int* np_; const int* ep_;
  if (g < 8){ np_ = hypT + (size_t)g*2*NNZ; ep_ = np_ + NNZ; }
  else      { np_ = hyp;                    ep_ = hyp + NNZ; }
  int nd = np_[i], ed = ep_[i];
  u32 i1 = (u32)g*GSZ + (u32)nd*SE + (u32)ed;
  atomicAdd(cHm  + (i1>>2), 1u << ((i1&3)*8));
  u32 i2 = (u32)g*GSZ + (u32)ed*SE + (u32)nd;
  atomicAdd(cHmT + (i2>>2), 1u << ((i2&3)*8));
}

__global__ __launch_bounds__(64) void k_deg(const u32* __restrict__ cHm,
                                            const u32* __restrict__ cHmT,
                                            float* __restrict__ Dinv,
                                            float* __restrict__ Binv){
  int r = blockIdx.x, g = blockIdx.y, which = blockIdx.z;
  const u32* base = (which==0 ? cHm : cHmT) + ((size_t)g*GSZ + (size_t)r*SE)/4;
  int tid = threadIdx.x;
  u32 s = 0;
  for (int k = tid; k < NW; k += 64){
    u32 w = base[k];
    s += (w & 0xFFu) + ((w>>8)&0xFFu) + ((w>>16)&0xFFu) + ((w>>24)&0xFFu);
  }
  for (int off = 32; off; off >>= 1) s += __shfl_down(s, off);
  if (tid == 0){
    float v = s ? 1.f/(float)s : 0.f;
    (which==0 ? Dinv : Binv)[g*N + r] = v;
  }
}

// GRU: 4 tickers per 256-thread block (4 waves), float4 weight staging
__global__ __launch_bounds__(256) void k_gru(const float* __restrict__ price,
                                             const float* __restrict__ Wih,
                                             const float* __restrict__ Whh,
                                             const float* __restrict__ bih,
                                             const float* __restrict__ bhh,
                                             float* __restrict__ ctx,
                                             float* __restrict__ last){
  __shared__ float sWhh[192*64];
  __shared__ float sWih[192*F_IN];
  __shared__ float sbih[192], sbhh[192];
  __shared__ float sh[4][64];
  __shared__ float sx[4][T*F_IN];
  int tid = threadIdx.x, w = tid>>6, lane = tid&63;
  int n = blockIdx.x*4 + w;
  for (int k = tid; k < 3072; k += 256) ((float4*)sWhh)[k] = ((const float4*)Whh)[k];
  for (int k = tid; k < 240;  k += 256) ((float4*)sWih)[k] = ((const float4*)Wih)[k];
  for (int k = tid; k < 48;   k += 256) ((float4*)sbih)[k] = ((const float4*)bih)[k];
  for (int k = tid; k < 48;   k += 256) ((float4*)sbhh)[k] = ((const float4*)bhh)[k];
  if (n < N){ for (int k = lane; k < T*F_IN; k += 64) sx[w][k] = price[(size_t)n*T*F_IN + k]; }
  else      { for (int k = lane; k < T*F_IN; k += 64) sx[w][k] = 0.f; }
  sh[w][lane] = 0.f;
  __syncthreads();
  for (int t = 0; t < T; t++){
    float ir = sbih[lane], iz = sbih[64+lane], inn = sbih[128+lane];
    #pragma unroll
    for (int d = 0; d < F_IN; d++){
      float x = sx[w][t*F_IN + d];
      ir  += x * sWih[lane*F_IN + d];
      iz  += x * sWih[(64+lane)*F_IN + d];
      inn += x * sWih[(128+lane)*F_IN + d];
    }
    float hr = sbhh[lane], hz = sbhh[64+lane], hn = sbhh[128+lane];
    for (int d = 0; d < 64; d++){
      float hv = sh[w][d];
      hr += hv * sWhh[lane*64 + d];
      hz += hv * sWhh[(64+lane)*64 + d];
      hn += hv * sWhh[(128+lane)*64 + d];
    }
    float r  = 1.f/(1.f + expf(-(ir+hr)));
    float z  = 1.f/(1.f + expf(-(iz+hz)));
    float nn = tanhf(inn + r*hn);
    float hnew = (1.f - z)*nn + z*sh[w][lane];
    __syncthreads();
    sh[w][lane] = hnew;
    if (n < N) ctx[((size_t)n*T + t)*H + lane] = hnew;
    __syncthreads();
  }
  if (n < N) last[(size_t)n*H + lane] = sh[w][lane];
}

// attention: 4 tickers per 256-thread block
__global__ __launch_bounds__(256) void k_attn(const float* __restrict__ ctx,
                                              const float* __restrict__ last,
                                              const float* __restrict__ Win,
                                              const float* __restrict__ Wout,
                                              const float* __restrict__ ae,
                                              const float* __restrict__ ab,
                                              float* __restrict__ outp){
  __shared__ float sWin[4096];
  __shared__ float sWout[8192];
  __shared__ float sc[4][T*64];
  __shared__ float sl[4][64];
  __shared__ float sq[4][64];
  __shared__ float ss[4][T];
  __shared__ float sco[4][128];
  int tid = threadIdx.x, w = tid>>6, lane = tid&63;
  int n = blockIdx.x*4 + w;
  for (int k = tid; k < 1024; k += 256) ((float4*)sWin)[k]  = ((const float4*)Win)[k];
  for (int k = tid; k < 2048; k += 256) ((float4*)sWout)[k] = ((const float4*)Wout)[k];
  if (n < N){
    for (int k = lane; k < T*64; k += 64) sc[w][k] = ctx[(size_t)n*T*H + k];
    sl[w][lane] = last[(size_t)n*H + lane];
  } else {
    for (int k = lane; k < T*64; k += 64) sc[w][k] = 0.f;
    sl[w][lane] = 0.f;
  }
  __syncthreads();
  float q = 0.f;
  for (int d = 0; d < 64; d++) q += sl[w][d]*sWin[d*64 + lane];
  sq[w][lane] = q;
  __syncthreads();
  if (lane < T){
    float s = 0.f;
    for (int d = 0; d < 64; d++) s += sq[w][d]*sc[w][lane*64 + d];
    ss[w][lane] = s;
  }
  __syncthreads();
  float m = ss[w][0];
  for (int t = 1; t < T; t++) m = fmaxf(m, ss[w][t]);
  float wv[T]; float den = 0.f;
  for (int t = 0; t < T; t++){ wv[t] = expf(ss[w][t]-m); den += wv[t]; }
  float aen = (n < N) ? ae[n] : 0.f, abn = (n < N) ? ab[n] : 0.f;
  float mixs = 0.f;
  for (int t = 0; t < T; t++){
    float wt = wv[t]/den;
    float mx = wt * sc[w][t*64 + lane];
    float bt = expf(-abn * (float)(T-1-t));
    mixs += fmaxf(aen*mx*bt, 0.f) + mx;
  }
  sco[w][lane] = mixs; sco[w][64+lane] = q;
  __syncthreads();
  float o = 0.f;
  for (int k = 0; k < 128; k++) o += sco[w][k]*sWout[k*64 + lane];
  if (n < N) outp[(size_t)n*H + lane] = tanhf(o);
}

// xt[g][rl][f] = (rl<1026) ? x[g][rl] @ theta : 0   (padded to KP rows)
__global__ __launch_bounds__(256) void k_xtheta(const float* __restrict__ x,
                                                const float* __restrict__ theta,
                                                float* __restrict__ xt){
  __shared__ float sth[64*64];
  __shared__ float sx[4][64];
  int tid = threadIdx.x;
  for (int k = tid; k < 1024; k += 256) ((float4*)sth)[k] = ((const float4*)theta)[k];
  int w = tid >> 6, f = tid & 63;
  int g = blockIdx.y;
  int rl = blockIdx.x*4 + w;
  bool valid = (rl < N);
  if (valid) sx[w][f] = x[((size_t)g*N + rl)*64 + f];
  __syncthreads();
  float acc = 0.f;
  if (valid){
    for (int d = 0; d < 64; d++) acc += sx[w][d]*sth[d*64 + f];
  }
  xt[((size_t)g*KP + rl)*64 + f] = acc;
}

// dense GEMM: Y[row][f] = epilogue( sum_k A_u8[row][k] * X[k][f] )
// A: u8 count matrix (row stride SE bytes), rows valid < 1026, K padded 1056 (zero pad)
// X: [KP][64] per graph (or shared), zero-padded rows 1026..1055
// mode 0 (pass A): Y=[g][KP][64], scale=Binv, pad rows stored as 0
// mode 1 (pass B): Y=[g][N][64],  scale=Dinv, +bias, leaky
__global__ __launch_bounds__(256) void k_gemm(const u32* __restrict__ Amat,
                                              const float* __restrict__ X,
                                              int x_per_graph,
                                              const float* __restrict__ scale,
                                              const float* __restrict__ bias,
                                              int mode,
                                              float* __restrict__ Y){
  __shared__ float sX[KT][64];
  __shared__ u32 sA[MT][KT/4];
  int m0 = blockIdx.x * MT;
  int g  = blockIdx.y;
  int tid = threadIdx.x;
  const u32* Ag = Amat + (size_t)g*(GSZ/4);
  const float* Xg = X + (x_per_graph ? (size_t)g*KP*64 : (size_t)0);
  int w = tid>>6, f = tid&63;
  int r0 = w*8;
  float acc[8];
  #pragma unroll
  for (int i=0;i<8;i++) acc[i]=0.f;
  for (int ks=0; ks<KSTEPS; ks++){
    int k0 = ks*KT;
    #pragma unroll
    for (int i=0;i<6;i++){
      int idx = tid + i*256;            // 0..1535 over 96 rows x 16 float4
      int row = idx>>4, c4 = idx&15;
      float4 v = ((const float4*)(Xg + (size_t)(k0+row)*64))[c4];
      ((float4*)&sX[row][0])[c4] = v;
    }
    #pragma unroll
    for (int i=0;i<3;i++){
      int idx = tid + i*256;            // 0..767 over 32 rows x 24 words
      int row = idx/24, wd = idx - row*24;
      int grow = m0 + row;
      u32 v = 0;
      if (grow < N) v = Ag[(size_t)grow*NW + (k0>>2) + wd];
      sA[row][wd] = v;
    }
    __syncthreads();
    #pragma unroll 4
    for (int kkb = 0; kkb < KT/4; kkb++){
      float x0 = sX[kkb*4+0][f];
      float x1 = sX[kkb*4+1][f];
      float x2 = sX[kkb*4+2][f];
      float x3 = sX[kkb*4+3][f];
      #pragma unroll
      for (int i=0;i<8;i++){
        u32 a = sA[r0+i][kkb];
        if (__builtin_amdgcn_readfirstlane((int)a)){   // wave-uniform skip
          acc[i] = fmaf((float)(a & 0xFFu),         x0, acc[i]);
          acc[i] = fmaf((float)((a >> 8)  & 0xFFu), x1, acc[i]);
          acc[i] = fmaf((float)((a >> 16) & 0xFFu), x2, acc[i]);
          acc[i] = fmaf((float)(a >> 24),           x3, acc[i]);
        }
      }
    }
    __syncthreads();
  }
  #pragma unroll
  for (int i=0;i<8;i++){
    int r = m0 + r0 + i;
    if (mode == 0){
      float v = (r < N) ? acc[i]*scale[g*N + r] : 0.f;
      Y[((size_t)g*KP + r)*64 + f] = v;
    } else if (r < N){
      float v = acc[i]*scale[g*N + r] + bias[f];
      Y[((size_t)g*N + r)*64 + f] = leakyf(v);
    }
  }
}

__global__ __launch_bounds__(256) void k_bmean(const float* __restrict__ x2,
                                               float* __restrict__ bout){
  int k = blockIdx.x, tid = threadIdx.x;
  const float* a = x2 + (size_t)k*N*H;
  const float* c = x2 + (size_t)(k+1)*N*H;
  float s = 0.f;
  for (int i = tid; i < N*H; i += 256) s += c[i] - a[i];
  __shared__ float red[256];
  red[tid] = s; __syncthreads();
  for (int off = 128; off; off >>= 1){ if (tid < off) red[tid] += red[tid+off]; __syncthreads(); }
  if (tid == 0) bout[k] = red[0] / (float)(N*H);
}

__global__ __launch_bounds__(256) void k_zred(const float* __restrict__ x2,
                                              const float* __restrict__ bout,
                                              const float* __restrict__ a_param,
                                              float* __restrict__ zout){
  int k = blockIdx.x, tid = threadIdx.x;
  const float* a = x2 + (size_t)k*N*H;
  const float* c = x2 + (size_t)(k+1)*N*H;
  float bk = bout[k], ap = a_param[k];
  float s = 0.f;
  for (int i = tid; i < N*H; i += 256){
    float sub = c[i] - a[i];
    float U = 1.f/(1.f + ap*(bk - sub));
    s += (U*sub)/U;
  }
  __shared__ float red[256];
  red[tid] = s; __syncthreads();
  for (int off = 128; off; off >>= 1){ if (tid < off) red[tid] += red[tid+off]; __syncthreads(); }
  if (tid == 0) zout[k] = red[0];
}

__global__ __launch_bounds__(64) void k_wattn(const float* __restrict__ z,
                                              const float* __restrict__ w1,
                                              const float* __restrict__ w2,
                                              float* __restrict__ wa){
  __shared__ float sz[TM], sy[64], sv[TM];
  int tid = threadIdx.x;
  if (tid < TM) sz[tid] = z[tid];
  __syncthreads();
  float y = 0.f;
  for (int kk = 0; kk < TM; kk++) y += w1[tid*TM + kk]*sz[kk];
  sy[tid] = leakyf(y);
  __syncthreads();
  if (tid < TM){
    float v = 0.f;
    for (int d = 0; d < 64; d++) v += w2[tid*64 + d]*sy[d];
    sv[tid] = v;
  }
  __syncthreads();
  if (tid == 0){
    float m = sv[0];
    for (int t = 1; t < TM; t++) m = fmaxf(m, sv[t]);
    float e[TM]; float den = 0.f;
    for (int t = 0; t < TM; t++){ e[t] = expf(sv[t]-m); den += e[t]; }
    for (int t = 0; t < TM; t++) wa[t] = e[t]/den;
  }
}

__global__ __launch_bounds__(256) void k_final(const float* __restrict__ x2,
                                               const float* __restrict__ wa,
                                               const float* __restrict__ Wl,
                                               const float* __restrict__ bl,
                                               const int* __restrict__ flag,
                                               void* __restrict__ outv){
  int n = blockIdx.x*256 + threadIdx.x;
  if (n >= N) return;
  float w0 = wa[0], w2v = wa[2];
  float acc = bl[0];
  for (int h = 0; h < 64; h++){
    float xg = x2[(size_t)8*N*H + (size_t)n*64 + h];
    float s0 = x2[(size_t)1*N*H + (size_t)n*64 + h] - x2[(size_t)0*N*H + (size_t)n*64 + h];
    float s2 = x2[(size_t)3*N*H + (size_t)n*64 + h] - x2[(size_t)2*N*H + (size_t)n*64 + h];
    float xx = w0*s0 + w2v*s2;
    acc += xg*Wl[h] + xx*Wl[64 + h];
  }
  float r = leakyf(acc);
  if (*flag) ((float*)outv)[n] = r;
  else       ((__hip_bfloat16*)outv)[n] = __float2bfloat16(r);
}

extern "C" void kernel_launch(void* const* d_in, const int* in_sizes, int n_in,
                              void* d_out, int out_size, void* d_ws, size_t ws_size,
                              hipStream_t stream) {
  const int* hypT = (const int*)d_in[1];
  const int* hyp  = (const int*)d_in[2];

  char* ws = (char*)d_ws;
  float* cv  = (float*)ws;
  int* flag  = (int*)(cv + TOT_CVT);
  u32* cHm   = (u32*)(ws + (size_t)CVT_PAD*4);
  u32* cHmT  = (u32*)(ws + (size_t)CVT_PAD*4 + (size_t)NG*GSZ);
  float* fp  = (float*)(ws + (size_t)CVT_PAD*4 + (size_t)2*NG*GSZ);
  float* Dinv = fp;                 fp += NG*N;
  float* Binv = fp;                 fp += NG*E;
  float* ctx  = fp;                 fp += (size_t)N*T*H;
  float* last = fp;                 fp += (size_t)N*H;
  float* outp = fp;                 fp += (size_t)N*H;
  float* xt1  = fp;                 fp += (size_t)KP*H;
  float* ebuf = fp;                 fp += (size_t)NG*KP*H;
  float* x1   = fp;                 fp += (size_t)NG*N*H;
  float* xt2  = fp;                 fp += (size_t)NG*KP*H;
  float* x2   = fp;                 fp += (size_t)NG*N*H;
  float* bv   = fp;                 fp += TM;
  float* zv   = fp;                 fp += TM;
  float* wa   = fp;                 fp += TM;

  const float* price  = cv + OFF_PRICE;
  const float* Wih    = cv + OFF_WIH;
  const float* Whh    = cv + OFF_WHH;
  const float* bih    = cv + OFF_BIH;
  const float* bhh    = cv + OFF_BHH;
  const float* Win    = cv + OFF_WIN;
  const float* Wout   = cv + OFF_WOUT;
  const float* ae     = cv + OFF_AE;
  const float* ab     = cv + OFF_AB;
  const float* theta1 = cv + OFF_TH1;
  const float* bias1  = cv + OFF_B1;
  const float* theta2 = cv + OFF_TH2;
  const float* bias2  = cv + OFF_B2;
  const float* w1     = cv + OFF_W1;
  const float* w2     = cv + OFF_W2;
  const float* a_par  = cv + OFF_APAR;
  const float* Wl     = cv + OFF_WL;
  const float* bl     = cv + OFF_BL;

  hipMemsetAsync(cHm, 0, (size_t)2*NG*GSZ, stream);

  k_detect<<<1, 64, 0, stream>>>((const unsigned short*)d_in[3], flag);
  CvtPtrs ps;
  ps.p[0]=d_in[0];  ps.p[1]=d_in[3];  ps.p[2]=d_in[4];  ps.p[3]=d_in[5];
  ps.p[4]=d_in[6];  ps.p[5]=d_in[7];  ps.p[6]=d_in[8];  ps.p[7]=d_in[9];
  ps.p[8]=d_in[10]; ps.p[9]=d_in[11]; ps.p[10]=d_in[12]; ps.p[11]=d_in[13];
  ps.p[12]=d_in[14]; ps.p[13]=d_in[15]; ps.p[14]=d_in[16]; ps.p[15]=d_in[17];
  ps.p[16]=d_in[18]; ps.p[17]=d_in[19];
  k_cvt<<<(TOT_CVT+255)/256, 256, 0, stream>>>(flag, ps, cv);

  k_build<<<dim3((NNZ+255)/256, NG), 256, 0, stream>>>(hypT, hyp, cHm, cHmT);
  k_deg  <<<dim3(N, NG, 2), 64, 0, stream>>>(cHm, cHmT, Dinv, Binv);
  k_gru  <<<(N+3)/4, 256, 0, stream>>>(price, Wih, Whh, bih, bhh, ctx, last);
  k_attn <<<(N+3)/4, 256, 0, stream>>>(ctx, last, Win, Wout, ae, ab, outp);

  // layer 1
  k_xtheta<<<dim3(KP/4, 1), 256, 0, stream>>>(outp, theta1, xt1);
  k_gemm<<<dim3(KP/MT, NG), 256, 0, stream>>>(cHmT, xt1, 0, Binv, nullptr, 0, ebuf);
  k_gemm<<<dim3(KP/MT, NG), 256, 0, stream>>>(cHm, ebuf, 1, Dinv, bias1, 1, x1);

  // layer 2
  k_xtheta<<<dim3(KP/4, NG), 256, 0, stream>>>(x1, theta2, xt2);
  k_gemm<<<dim3(KP/MT, NG), 256, 0, stream>>>(cHmT, xt2, 1, Binv, nullptr, 0, ebuf);
  k_gemm<<<dim3(KP/MT, NG), 256, 0, stream>>>(cHm, ebuf, 1, Dinv, bias2, 1, x2);

  k_bmean<<<TM, 256, 0, stream>>>(x2, bv);
  k_zred <<<TM, 256, 0, stream>>>(x2, bv, a_par, zv);
  k_wattn<<<1, 64, 0, stream>>>(zv, w1, w2, wa);
  k_final<<<(N+255)/256, 256, 0, stream>>>(x2, wa, Wl, bl, flag, d_out);
}

// Round 4
// 719.633 us; speedup vs baseline: 1.5170x; 1.5170x over previous
//
#include <hip/hip_runtime.h>
#include <hip/hip_bf16.h>
#include <math.h>

#define N 1026
#define T 8
#define H 64
#define F_IN 5
#define E 1026
#define NNZ 200000
#define TM 7
#define NG 9
#define SE 1056
#define NW (SE/4)
#define GSZ (N*SE)
#define KP 1056        // padded K (rows of padded X buffers)
#define MT 32          // GEMM rows per block
#define KT 96          // GEMM k-tile (96*11 = 1056 exactly)
#define KSTEPS 11
#define WT 193         // transposed Whh LDS stride (193 % 32 == 1 -> conflict-free)

#define OFF_PRICE   0
#define OFF_WIH     41040
#define OFF_WHH     42000
#define OFF_BIH     54288
#define OFF_BHH     54480
#define OFF_WIN     54672
#define OFF_WOUT    58768
#define OFF_AE      66960
#define OFF_AB      67986
#define OFF_TH1     69012
#define OFF_B1      73108
#define OFF_TH2     73172
#define OFF_B2      77268
#define OFF_W1      77332
#define OFF_W2      77780
#define OFF_APAR    78228
#define OFF_WL      78235
#define OFF_BL      78363
#define TOT_CVT     78364
#define CVT_PAD     78368

typedef unsigned int u32;

__device__ __forceinline__ float leakyf(float x){ return x >= 0.f ? x : 0.2f*x; }
__device__ __forceinline__ float bfbits2f(unsigned short u){
  union { unsigned int i; float f; } c; c.i = ((unsigned int)u) << 16; return c.f;
}

__global__ __launch_bounds__(64) void k_detect(const unsigned short* __restrict__ w,
                                               int* __restrict__ flag){
  int tid = threadIdx.x;
  int big = 0;
  for (int k = tid; k < 960; k += 64){
    float a = fabsf(bfbits2f(w[k]));
    if (!(a < 1e3f)) big = 1;
  }
  unsigned long long any = __ballot(big != 0);
  if (tid == 0) *flag = (any != 0ull) ? 1 : 0;
}

struct CvtPtrs { const void* p[18]; };

__global__ __launch_bounds__(256) void k_cvt(const int* __restrict__ flag,
                                             CvtPtrs ps, float* __restrict__ dst){
  const int offs[19] = {OFF_PRICE, OFF_WIH, OFF_WHH, OFF_BIH, OFF_BHH, OFF_WIN,
                        OFF_WOUT, OFF_AE, OFF_AB, OFF_TH1, OFF_B1, OFF_TH2,
                        OFF_B2, OFF_W1, OFF_W2, OFF_APAR, OFF_WL, OFF_BL, TOT_CVT};
  int i = blockIdx.x*256 + threadIdx.x;
  if (i >= TOT_CVT) return;
  int t = 0;
  #pragma unroll
  for (int k = 1; k < 18; k++) if (i >= offs[k]) t = k;
  int j = i - offs[t];
  float v;
  if (*flag) v = ((const float*)ps.p[t])[j];
  else       v = bfbits2f(((const unsigned short*)ps.p[t])[j]);
  dst[i] = v;
}

__global__ __launch_bounds__(256) void k_build(const int* __restrict__ hypT,
                                               const int* __restrict__ hyp,
                                               u32* __restrict__ cHm,
                                               u32* __restrict__ cHmT){
  int g = blockIdx.y;
  int i = blockIdx.x*256 + threadIdx.x;
  if (i >= NNZ) return;
  const int* np_; const int* ep_;
  if (g < 8){ np_ = hypT + (size_t)g*2*NNZ; ep_ = np_ + NNZ; }
  else      { np_ = hyp;                    ep_ = hyp + NNZ; }
  int nd = np_[i], ed = ep_[i];
  u32 i1 = (u32)g*GSZ + (u32)nd*SE + (u32)ed;
  atomicAdd(cHm  + (i1>>2), 1u << ((i1&3)*8));
  u32 i2 = (u32)g*GSZ + (u32)ed*SE + (u32)nd;
  atomicAdd(cHmT + (i2>>2), 1u << ((i2&3)*8));
}

__global__ __launch_bounds__(64) void k_deg(const u32* __restrict__ cHm,
                                            const u32* __restrict__ cHmT,
                                            float* __restrict__ Dinv,
                                            float* __restrict__ Binv){
  int r = blockIdx.x, g = blockIdx.y, which = blockIdx.z;
  const u32* base = (which==0 ? cHm : cHmT) + ((size_t)g*GSZ + (size_t)r*SE)/4;
  int tid = threadIdx.x;
  u32 s = 0;
  for (int k = tid; k < NW; k += 64){
    u32 w = base[k];
    s += (w & 0xFFu) + ((w>>8)&0xFFu) + ((w>>16)&0xFFu) + ((w>>24)&0xFFu);
  }
  for (int off = 32; off; off >>= 1) s += __shfl_down(s, off);
  if (tid == 0){
    float v = s ? 1.f/(float)s : 0.f;
    (which==0 ? Dinv : Binv)[g*N + r] = v;
  }
}

// GRU: 4 tickers per 256-thread block; WhhT staged transposed (stride 193)
// so inner-loop reads are conflict-free (lane-consecutive), sh[d] is broadcast.
__global__ __launch_bounds__(256) void k_gru(const float* __restrict__ price,
                                             const float* __restrict__ Wih,
                                             const float* __restrict__ Whh,
                                             const float* __restrict__ bih,
                                             const float* __restrict__ bhh,
                                             float* __restrict__ ctx,
                                             float* __restrict__ last){
  __shared__ float sWhhT[64*WT];        // [d][j], j in 0..191
  __shared__ float sWih[192*F_IN];
  __shared__ float sbih[192], sbhh[192];
  __shared__ float sh[4][64];
  __shared__ float sx[4][T*F_IN];
  int tid = threadIdx.x, w = tid>>6, lane = tid&63;
  int n = blockIdx.x*4 + w;
  // transposed staging: read Whh[j*64+d] coalesced, write stride-193 (conflict-free)
  for (int idx = tid; idx < 192*64; idx += 256){
    int j = idx >> 6, d = idx & 63;
    sWhhT[d*WT + j] = Whh[idx];
  }
  for (int k = tid; k < 192*F_IN; k += 256) sWih[k] = Wih[k];
  for (int k = tid; k < 192;      k += 256){ sbih[k] = bih[k]; sbhh[k] = bhh[k]; }
  if (n < N){ for (int k = lane; k < T*F_IN; k += 64) sx[w][k] = price[(size_t)n*T*F_IN + k]; }
  else      { for (int k = lane; k < T*F_IN; k += 64) sx[w][k] = 0.f; }
  sh[w][lane] = 0.f;
  __syncthreads();
  for (int t = 0; t < T; t++){
    float ir = sbih[lane], iz = sbih[64+lane], inn = sbih[128+lane];
    #pragma unroll
    for (int d = 0; d < F_IN; d++){
      float x = sx[w][t*F_IN + d];
      ir  += x * sWih[lane*F_IN + d];
      iz  += x * sWih[(64+lane)*F_IN + d];
      inn += x * sWih[(128+lane)*F_IN + d];
    }
    float hr = sbhh[lane], hz = sbhh[64+lane], hn = sbhh[128+lane];
    for (int d = 0; d < 64; d++){
      float hv = sh[w][d];                 // broadcast (free)
      const float* wr = &sWhhT[d*WT];
      hr += hv * wr[lane];                 // lane-consecutive: conflict-free
      hz += hv * wr[64 + lane];
      hn += hv * wr[128 + lane];
    }
    float r  = 1.f/(1.f + expf(-(ir+hr)));
    float z  = 1.f/(1.f + expf(-(iz+hz)));
    float nn = tanhf(inn + r*hn);
    float hnew = (1.f - z)*nn + z*sh[w][lane];
    __syncthreads();
    sh[w][lane] = hnew;
    if (n < N) ctx[((size_t)n*T + t)*H + lane] = hnew;
    __syncthreads();
  }
  if (n < N) last[(size_t)n*H + lane] = sh[w][lane];
}

// attention: 4 tickers per 256-thread block (all LDS reads lane-consecutive or broadcast)
__global__ __launch_bounds__(256) void k_attn(const float* __restrict__ ctx,
                                              const float* __restrict__ last,
                                              const float* __restrict__ Win,
                                              const float* __restrict__ Wout,
                                              const float* __restrict__ ae,
                                              const float* __restrict__ ab,
                                              float* __restrict__ outp){
  __shared__ float sWin[4096];
  __shared__ float sWout[8192];
  __shared__ float sc[4][T*64];
  __shared__ float sl[4][64];
  __shared__ float sq[4][64];
  __shared__ float ss[4][T];
  __shared__ float sco[4][128];
  int tid = threadIdx.x, w = tid>>6, lane = tid&63;
  int n = blockIdx.x*4 + w;
  for (int k = tid; k < 1024; k += 256) ((float4*)sWin)[k]  = ((const float4*)Win)[k];
  for (int k = tid; k < 2048; k += 256) ((float4*)sWout)[k] = ((const float4*)Wout)[k];
  if (n < N){
    for (int k = lane; k < T*64; k += 64) sc[w][k] = ctx[(size_t)n*T*H + k];
    sl[w][lane] = last[(size_t)n*H + lane];
  } else {
    for (int k = lane; k < T*64; k += 64) sc[w][k] = 0.f;
    sl[w][lane] = 0.f;
  }
  __syncthreads();
  float q = 0.f;
  for (int d = 0; d < 64; d++) q += sl[w][d]*sWin[d*64 + lane];
  sq[w][lane] = q;
  __syncthreads();
  if (lane < T){
    float s = 0.f;
    for (int d = 0; d < 64; d++) s += sq[w][d]*sc[w][lane*64 + d];
    ss[w][lane] = s;
  }
  __syncthreads();
  float m = ss[w][0];
  for (int t = 1; t < T; t++) m = fmaxf(m, ss[w][t]);
  float wv[T]; float den = 0.f;
  for (int t = 0; t < T; t++){ wv[t] = expf(ss[w][t]-m); den += wv[t]; }
  float aen = (n < N) ? ae[n] : 0.f, abn = (n < N) ? ab[n] : 0.f;
  float mixs = 0.f;
  for (int t = 0; t < T; t++){
    float wt = wv[t]/den;
    float mx = wt * sc[w][t*64 + lane];
    float bt = expf(-abn * (float)(T-1-t));
    mixs += fmaxf(aen*mx*bt, 0.f) + mx;
  }
  sco[w][lane] = mixs; sco[w][64+lane] = q;
  __syncthreads();
  float o = 0.f;
  for (int k = 0; k < 128; k++) o += sco[w][k]*sWout[k*64 + lane];
  if (n < N) outp[(size_t)n*H + lane] = tanhf(o);
}

// xt[g][rl][f] = (rl<1026) ? x[g][rl] @ theta : 0   (padded to KP rows)
__global__ __launch_bounds__(256) void k_xtheta(const float* __restrict__ x,
                                                const float* __restrict__ theta,
                                                float* __restrict__ xt){
  __shared__ float sth[64*64];
  __shared__ float sx[4][64];
  int tid = threadIdx.x;
  for (int k = tid; k < 1024; k += 256) ((float4*)sth)[k] = ((const float4*)theta)[k];
  int w = tid >> 6, f = tid & 63;
  int g = blockIdx.y;
  int rl = blockIdx.x*4 + w;
  bool valid = (rl < N);
  if (valid) sx[w][f] = x[((size_t)g*N + rl)*64 + f];
  __syncthreads();
  float acc = 0.f;
  if (valid){
    for (int d = 0; d < 64; d++) acc += sx[w][d]*sth[d*64 + f];
  }
  xt[((size_t)g*KP + rl)*64 + f] = acc;
}

// dense GEMM: Y[row][f] = epilogue( sum_k A_u8[row][k] * X[k][f] )
// Branch-free inner loop: cvt_f32_ubyte + fmaf (fmaf(0,x,acc)==acc exactly),
// so the compiler can pipeline the LDS reads with lgkmcnt(N).
__global__ __launch_bounds__(256) void k_gemm(const u32* __restrict__ Amat,
                                              const float* __restrict__ X,
                                              int x_per_graph,
                                              const float* __restrict__ scale,
                                              const float* __restrict__ bias,
                                              int mode,
                                              float* __restrict__ Y){
  __shared__ float sX[KT][64];
  __shared__ u32 sA[MT][KT/4];
  int m0 = blockIdx.x * MT;
  int g  = blockIdx.y;
  int tid = threadIdx.x;
  const u32* Ag = Amat + (size_t)g*(GSZ/4);
  const float* Xg = X + (x_per_graph ? (size_t)g*KP*64 : (size_t)0);
  int w = tid>>6, f = tid&63;
  int r0 = w*8;
  float acc[8];
  #pragma unroll
  for (int i=0;i<8;i++) acc[i]=0.f;
  for (int ks=0; ks<KSTEPS; ks++){
    int k0 = ks*KT;
    #pragma unroll
    for (int i=0;i<6;i++){
      int idx = tid + i*256;            // 0..1535 over 96 rows x 16 float4
      int row = idx>>4, c4 = idx&15;
      float4 v = ((const float4*)(Xg + (size_t)(k0+row)*64))[c4];
      ((float4*)&sX[row][0])[c4] = v;
    }
    #pragma unroll
    for (int i=0;i<3;i++){
      int idx = tid + i*256;            // 0..767 over 32 rows x 24 words
      int row = idx/24, wd = idx - row*24;
      int grow = m0 + row;
      u32 v = 0;
      if (grow < N) v = Ag[(size_t)grow*NW + (k0>>2) + wd];
      sA[row][wd] = v;
    }
    __syncthreads();
    #pragma unroll 4
    for (int kkb = 0; kkb < KT/4; kkb++){
      float x0 = sX[kkb*4+0][f];
      float x1 = sX[kkb*4+1][f];
      float x2 = sX[kkb*4+2][f];
      float x3 = sX[kkb*4+3][f];
      #pragma unroll
      for (int i=0;i<8;i++){
        u32 a = sA[r0+i][kkb];          // wave-uniform broadcast
        acc[i] = fmaf((float)(a & 0xFFu),         x0, acc[i]);
        acc[i] = fmaf((float)((a >> 8)  & 0xFFu), x1, acc[i]);
        acc[i] = fmaf((float)((a >> 16) & 0xFFu), x2, acc[i]);
        acc[i] = fmaf((float)(a >> 24),           x3, acc[i]);
      }
    }
    __syncthreads();
  }
  #pragma unroll
  for (int i=0;i<8;i++){
    int r = m0 + r0 + i;
    if (mode == 0){
      float v = (r < N) ? acc[i]*scale[g*N + r] : 0.f;
      Y[((size_t)g*KP + r)*64 + f] = v;
    } else if (r < N){
      float v = acc[i]*scale[g*N + r] + bias[f];
      Y[((size_t)g*N + r)*64 + f] = leakyf(v);
    }
  }
}

__global__ __launch_bounds__(256) void k_bmean(const float* __restrict__ x2,
                                               float* __restrict__ bout){
  int k = blockIdx.x, tid = threadIdx.x;
  const float* a = x2 + (size_t)k*N*H;
  const float* c = x2 + (size_t)(k+1)*N*H;
  float s = 0.f;
  for (int i = tid; i < N*H; i += 256) s += c[i] - a[i];
  __shared__ float red[256];
  red[tid] = s; __syncthreads();
  for (int off = 128; off; off >>= 1){ if (tid < off) red[tid] += red[tid+off]; __syncthreads(); }
  if (tid == 0) bout[k] = red[0] / (float)(N*H);
}

__global__ __launch_bounds__(256) void k_zred(const float* __restrict__ x2,
                                              const float* __restrict__ bout,
                                              const float* __restrict__ a_param,
                                              float* __restrict__ zout){
  int k = blockIdx.x, tid = threadIdx.x;
  const float* a = x2 + (size_t)k*N*H;
  const float* c = x2 + (size_t)(k+1)*N*H;
  float bk = bout[k], ap = a_param[k];
  float s = 0.f;
  for (int i = tid; i < N*H; i += 256){
    float sub = c[i] - a[i];
    float U = 1.f/(1.f + ap*(bk - sub));
    s += (U*sub)/U;
  }
  __shared__ float red[256];
  red[tid] = s; __syncthreads();
  for (int off = 128; off; off >>= 1){ if (tid < off) red[tid] += red[tid+off]; __syncthreads(); }
  if (tid == 0) zout[k] = red[0];
}

__global__ __launch_bounds__(64) void k_wattn(const float* __restrict__ z,
                                              const float* __restrict__ w1,
                                              const float* __restrict__ w2,
                                              float* __restrict__ wa){
  __shared__ float sz[TM], sy[64], sv[TM];
  int tid = threadIdx.x;
  if (tid < TM) sz[tid] = z[tid];
  __syncthreads();
  float y = 0.f;
  for (int kk = 0; kk < TM; kk++) y += w1[tid*TM + kk]*sz[kk];
  sy[tid] = leakyf(y);
  __syncthreads();
  if (tid < TM){
    float v = 0.f;
    for (int d = 0; d < 64; d++) v += w2[tid*64 + d]*sy[d];
    sv[tid] = v;
  }
  __syncthreads();
  if (tid == 0){
    float m = sv[0];
    for (int t = 1; t < TM; t++) m = fmaxf(m, sv[t]);
    float e[TM]; float den = 0.f;
    for (int t = 0; t < TM; t++){ e[t] = expf(sv[t]-m); den += e[t]; }
    for (int t = 0; t < TM; t++) wa[t] = e[t]/den;
  }
}

__global__ __launch_bounds__(256) void k_final(const float* __restrict__ x2,
                                               const float* __restrict__ wa,
                                               const float* __restrict__ Wl,
                                               const float* __restrict__ bl,
                                               const int* __restrict__ flag,
                                               void* __restrict__ outv){
  int n = blockIdx.x*256 + threadIdx.x;
  if (n >= N) return;
  float w0 = wa[0], w2v = wa[2];
  float acc = bl[0];
  for (int h = 0; h < 64; h++){
    float xg = x2[(size_t)8*N*H + (size_t)n*64 + h];
    float s0 = x2[(size_t)1*N*H + (size_t)n*64 + h] - x2[(size_t)0*N*H + (size_t)n*64 + h];
    float s2 = x2[(size_t)3*N*H + (size_t)n*64 + h] - x2[(size_t)2*N*H + (size_t)n*64 + h];
    float xx = w0*s0 + w2v*s2;
    acc += xg*Wl[h] + xx*Wl[64 + h];
  }
  float r = leakyf(acc);
  if (*flag) ((float*)outv)[n] = r;
  else       ((__hip_bfloat16*)outv)[n] = __float2bfloat16(r);
}

extern "C" void kernel_launch(void* const* d_in, const int* in_sizes, int n_in,
                              void* d_out, int out_size, void* d_ws, size_t ws_size,
                              hipStream_t stream) {
  const int* hypT = (const int*)d_in[1];
  const int* hyp  = (const int*)d_in[2];

  char* ws = (char*)d_ws;
  float* cv  = (float*)ws;
  int* flag  = (int*)(cv + TOT_CVT);
  u32* cHm   = (u32*)(ws + (size_t)CVT_PAD*4);
  u32* cHmT  = (u32*)(ws + (size_t)CVT_PAD*4 + (size_t)NG*GSZ);
  float* fp  = (float*)(ws + (size_t)CVT_PAD*4 + (size_t)2*NG*GSZ);
  float* Dinv = fp;                 fp += NG*N;
  float* Binv = fp;                 fp += NG*E;
  float* ctx  = fp;                 fp += (size_t)N*T*H;
  float* last = fp;                 fp += (size_t)N*H;
  float* outp = fp;                 fp += (size_t)N*H;
  float* xt1  = fp;                 fp += (size_t)KP*H;
  float* ebuf = fp;                 fp += (size_t)NG*KP*H;
  float* x1   = fp;                 fp += (size_t)NG*N*H;
  float* xt2  = fp;                 fp += (size_t)NG*KP*H;
  float* x2   = fp;                 fp += (size_t)NG*N*H;
  float* bv   = fp;                 fp += TM;
  float* zv   = fp;                 fp += TM;
  float* wa   = fp;                 fp += TM;

  const float* price  = cv + OFF_PRICE;
  const float* Wih    = cv + OFF_WIH;
  const float* Whh    = cv + OFF_WHH;
  const float* bih    = cv + OFF_BIH;
  const float* bhh    = cv + OFF_BHH;
  const float* Win    = cv + OFF_WIN;
  const float* Wout   = cv + OFF_WOUT;
  const float* ae     = cv + OFF_AE;
  const float* ab     = cv + OFF_AB;
  const float* theta1 = cv + OFF_TH1;
  const float* bias1  = cv + OFF_B1;
  const float* theta2 = cv + OFF_TH2;
  const float* bias2  = cv + OFF_B2;
  const float* w1     = cv + OFF_W1;
  const float* w2     = cv + OFF_W2;
  const float* a_par  = cv + OFF_APAR;
  const float* Wl     = cv + OFF_WL;
  const float* bl     = cv + OFF_BL;

  hipMemsetAsync(cHm, 0, (size_t)2*NG*GSZ, stream);

  k_detect<<<1, 64, 0, stream>>>((const unsigned short*)d_in[3], flag);
  CvtPtrs ps;
  ps.p[0]=d_in[0];  ps.p[1]=d_in[3];  ps.p[2]=d_in[4];  ps.p[3]=d_in[5];
  ps.p[4]=d_in[6];  ps.p[5]=d_in[7];  ps.p[6]=d_in[8];  ps.p[7]=d_in[9];
  ps.p[8]=d_in[10]; ps.p[9]=d_in[11]; ps.p[10]=d_in[12]; ps.p[11]=d_in[13];
  ps.p[12]=d_in[14]; ps.p[13]=d_in[15]; ps.p[14]=d_in[16]; ps.p[15]=d_in[17];
  ps.p[16]=d_in[18]; ps.p[17]=d_in[19];
  k_cvt<<<(TOT_CVT+255)/256, 256, 0, stream>>>(flag, ps, cv);

  k_build<<<dim3((NNZ+255)/256, NG), 256, 0, stream>>>(hypT, hyp, cHm, cHmT);
  k_deg  <<<dim3(N, NG, 2), 64, 0, stream>>>(cHm, cHmT, Dinv, Binv);
  k_gru  <<<(N+3)/4, 256, 0, stream>>>(price, Wih, Whh, bih, bhh, ctx, last);
  k_attn <<<(N+3)/4, 256, 0, stream>>>(ctx, last, Win, Wout, ae, ab, outp);

  // layer 1
  k_xtheta<<<dim3(KP/4, 1), 256, 0, stream>>>(outp, theta1, xt1);
  k_gemm<<<dim3(KP/MT, NG), 256, 0, stream>>>(cHmT, xt1, 0, Binv, nullptr, 0, ebuf);
  k_gemm<<<dim3(KP/MT, NG), 256, 0, stream>>>(cHm, ebuf, 1, Dinv, bias1, 1, x1);

  // layer 2
  k_xtheta<<<dim3(KP/4, NG), 256, 0, stream>>>(x1, theta2, xt2);
  k_gemm<<<dim3(KP/MT, NG), 256, 0, stream>>>(cHmT, xt2, 1, Binv, nullptr, 0, ebuf);
  k_gemm<<<dim3(KP/MT, NG), 256, 0, stream>>>(cHm, ebuf, 1, Dinv, bias2, 1, x2);

  k_bmean<<<TM, 256, 0, stream>>>(x2, bv);
  k_zred <<<TM, 256, 0, stream>>>(x2, bv, a_par, zv);
  k_wattn<<<1, 64, 0, stream>>>(zv, w1, w2, wa);
  k_final<<<(N+255)/256, 256, 0, stream>>>(x2, wa, Wl, bl, flag, d_out);
}

// Round 5
// 517.735 us; speedup vs baseline: 2.1086x; 1.3900x over previous
//
#include <hip/hip_runtime.h>
#include <hip/hip_bf16.h>
#include <math.h>

#define N 1026
#define T 8
#define H 64
#define F_IN 5
#define E 1026
#define NNZ 200000
#define TM 7
#define NG 9
#define KP 1056        // padded K / M for conv GEMMs
#define SB 528         // nibble-packed row stride in BYTES (1056 cols / 2)
#define NWB (SB/4)     // 132 u32 words per row
#define GSZB (N*SB)    // bytes per count matrix per graph
#define WT 193         // transposed Whh LDS stride (conflict-free)

#define OFF_PRICE   0
#define OFF_WIH     41040
#define OFF_WHH     42000
#define OFF_BIH     54288
#define OFF_BHH     54480
#define OFF_WIN     54672
#define OFF_WOUT    58768
#define OFF_AE      66960
#define OFF_AB      67986
#define OFF_TH1     69012
#define OFF_B1      73108
#define OFF_TH2     73172
#define OFF_B2      77268
#define OFF_W1      77332
#define OFF_W2      77780
#define OFF_APAR    78228
#define OFF_WL      78235
#define OFF_BL      78363
#define TOT_CVT     78364
#define CVT_PAD     78368

typedef unsigned int u32;
typedef unsigned short u16;
typedef short bf16x8 __attribute__((ext_vector_type(8)));
typedef float f32x4 __attribute__((ext_vector_type(4)));

__device__ __forceinline__ float leakyf(float x){ return x >= 0.f ? x : 0.2f*x; }
__device__ __forceinline__ float bfbits2f(u16 u){
  union { u32 i; float f; } c; c.i = ((u32)u) << 16; return c.f;
}
__device__ __forceinline__ u16 f2bf(float f){      // round-to-nearest-even
  u32 x = __builtin_bit_cast(u32, f);
  u32 r = x + 0x7FFFu + ((x >> 16) & 1u);
  return (u16)(r >> 16);
}

__global__ __launch_bounds__(64) void k_detect(const u16* __restrict__ w,
                                               int* __restrict__ flag){
  int tid = threadIdx.x;
  int big = 0;
  for (int k = tid; k < 960; k += 64){
    float a = fabsf(bfbits2f(w[k]));
    if (!(a < 1e3f)) big = 1;
  }
  unsigned long long any = __ballot(big != 0);
  if (tid == 0) *flag = (any != 0ull) ? 1 : 0;
}

struct CvtPtrs { const void* p[18]; };

__global__ __launch_bounds__(256) void k_cvt(const int* __restrict__ flag,
                                             CvtPtrs ps, float* __restrict__ dst){
  const int offs[19] = {OFF_PRICE, OFF_WIH, OFF_WHH, OFF_BIH, OFF_BHH, OFF_WIN,
                        OFF_WOUT, OFF_AE, OFF_AB, OFF_TH1, OFF_B1, OFF_TH2,
                        OFF_B2, OFF_W1, OFF_W2, OFF_APAR, OFF_WL, OFF_BL, TOT_CVT};
  int i = blockIdx.x*256 + threadIdx.x;
  if (i >= TOT_CVT) return;
  int t = 0;
  #pragma unroll
  for (int k = 1; k < 18; k++) if (i >= offs[k]) t = k;
  int j = i - offs[t];
  float v;
  if (*flag) v = ((const float*)ps.p[t])[j];
  else       v = bfbits2f(((const u16*)ps.p[t])[j]);
  dst[i] = v;
}

// nibble-packed incidence counts: cell (r,c) -> word r*NWB + (c>>3), shift (c&7)*4
__global__ __launch_bounds__(256) void k_build(const int* __restrict__ hypT,
                                               const int* __restrict__ hyp,
                                               u32* __restrict__ cHm,
                                               u32* __restrict__ cHmT){
  int g = blockIdx.y;
  int i = blockIdx.x*256 + threadIdx.x;
  if (i >= NNZ) return;
  const int* np_; const int* ep_;
  if (g < 8){ np_ = hypT + (size_t)g*2*NNZ; ep_ = np_ + NNZ; }
  else      { np_ = hyp;                    ep_ = hyp + NNZ; }
  int nd = np_[i], ed = ep_[i];
  u32 base = (u32)g*(GSZB/4);
  atomicAdd(cHm  + base + (u32)nd*NWB + (ed>>3), 1u << ((ed&7)*4));
  atomicAdd(cHmT + base + (u32)ed*NWB + (nd>>3), 1u << ((nd&7)*4));
}

__global__ __launch_bounds__(64) void k_deg(const u32* __restrict__ cHm,
                                            const u32* __restrict__ cHmT,
                                            float* __restrict__ Dinv,
                                            float* __restrict__ Binv){
  int r = blockIdx.x, g = blockIdx.y, which = blockIdx.z;
  const u32* base = (which==0 ? cHm : cHmT) + (size_t)g*(GSZB/4) + (size_t)r*NWB;
  int tid = threadIdx.x;
  u32 s = 0;
  for (int k = tid; k < NWB; k += 64){
    u32 w = base[k];
    u32 a = (w & 0x0F0F0F0Fu) + ((w >> 4) & 0x0F0F0F0Fu);
    s += (a & 0xFFu) + ((a>>8)&0xFFu) + ((a>>16)&0xFFu) + (a>>24);
  }
  for (int off = 32; off; off >>= 1) s += __shfl_down(s, off);
  if (tid == 0){
    float v = s ? 1.f/(float)s : 0.f;
    (which==0 ? Dinv : Binv)[g*N + r] = v;
  }
}

// GRU: 4 tickers per 256-thread block; WhhT transposed (stride 193, conflict-free)
__global__ __launch_bounds__(256) void k_gru(const float* __restrict__ price,
                                             const float* __restrict__ Wih,
                                             const float* __restrict__ Whh,
                                             const float* __restrict__ bih,
                                             const float* __restrict__ bhh,
                                             float* __restrict__ ctx,
                                             float* __restrict__ last){
  __shared__ float sWhhT[64*WT];
  __shared__ float sWih[192*F_IN];
  __shared__ float sbih[192], sbhh[192];
  __shared__ float sh[4][64];
  __shared__ float sx[4][T*F_IN];
  int tid = threadIdx.x, w = tid>>6, lane = tid&63;
  int n = blockIdx.x*4 + w;
  for (int idx = tid; idx < 192*64; idx += 256){
    int j = idx >> 6, d = idx & 63;
    sWhhT[d*WT + j] = Whh[idx];
  }
  for (int k = tid; k < 192*F_IN; k += 256) sWih[k] = Wih[k];
  for (int k = tid; k < 192;      k += 256){ sbih[k] = bih[k]; sbhh[k] = bhh[k]; }
  if (n < N){ for (int k = lane; k < T*F_IN; k += 64) sx[w][k] = price[(size_t)n*T*F_IN + k]; }
  else      { for (int k = lane; k < T*F_IN; k += 64) sx[w][k] = 0.f; }
  sh[w][lane] = 0.f;
  __syncthreads();
  for (int t = 0; t < T; t++){
    float ir = sbih[lane], iz = sbih[64+lane], inn = sbih[128+lane];
    #pragma unroll
    for (int d = 0; d < F_IN; d++){
      float x = sx[w][t*F_IN + d];
      ir  += x * sWih[lane*F_IN + d];
      iz  += x * sWih[(64+lane)*F_IN + d];
      inn += x * sWih[(128+lane)*F_IN + d];
    }
    float hr = sbhh[lane], hz = sbhh[64+lane], hn = sbhh[128+lane];
    for (int d = 0; d < 64; d++){
      float hv = sh[w][d];
      const float* wr = &sWhhT[d*WT];
      hr += hv * wr[lane];
      hz += hv * wr[64 + lane];
      hn += hv * wr[128 + lane];
    }
    float r  = 1.f/(1.f + expf(-(ir+hr)));
    float z  = 1.f/(1.f + expf(-(iz+hz)));
    float nn = tanhf(inn + r*hn);
    float hnew = (1.f - z)*nn + z*sh[w][lane];
    __syncthreads();
    sh[w][lane] = hnew;
    if (n < N) ctx[((size_t)n*T + t)*H + lane] = hnew;
    __syncthreads();
  }
  if (n < N) last[(size_t)n*H + lane] = sh[w][lane];
}

__global__ __launch_bounds__(256) void k_attn(const float* __restrict__ ctx,
                                              const float* __restrict__ last,
                                              const float* __restrict__ Win,
                                              const float* __restrict__ Wout,
                                              const float* __restrict__ ae,
                                              const float* __restrict__ ab,
                                              float* __restrict__ outp){
  __shared__ float sWin[4096];
  __shared__ float sWout[8192];
  __shared__ float sc[4][T*64];
  __shared__ float sl[4][64];
  __shared__ float sq[4][64];
  __shared__ float ss[4][T];
  __shared__ float sco[4][128];
  int tid = threadIdx.x, w = tid>>6, lane = tid&63;
  int n = blockIdx.x*4 + w;
  for (int k = tid; k < 1024; k += 256) ((float4*)sWin)[k]  = ((const float4*)Win)[k];
  for (int k = tid; k < 2048; k += 256) ((float4*)sWout)[k] = ((const float4*)Wout)[k];
  if (n < N){
    for (int k = lane; k < T*64; k += 64) sc[w][k] = ctx[(size_t)n*T*H + k];
    sl[w][lane] = last[(size_t)n*H + lane];
  } else {
    for (int k = lane; k < T*64; k += 64) sc[w][k] = 0.f;
    sl[w][lane] = 0.f;
  }
  __syncthreads();
  float q = 0.f;
  for (int d = 0; d < 64; d++) q += sl[w][d]*sWin[d*64 + lane];
  sq[w][lane] = q;
  __syncthreads();
  if (lane < T){
    float s = 0.f;
    for (int d = 0; d < 64; d++) s += sq[w][d]*sc[w][lane*64 + d];
    ss[w][lane] = s;
  }
  __syncthreads();
  float m = ss[w][0];
  for (int t = 1; t < T; t++) m = fmaxf(m, ss[w][t]);
  float wv[T]; float den = 0.f;
  for (int t = 0; t < T; t++){ wv[t] = expf(ss[w][t]-m); den += wv[t]; }
  float aen = (n < N) ? ae[n] : 0.f, abn = (n < N) ? ab[n] : 0.f;
  float mixs = 0.f;
  for (int t = 0; t < T; t++){
    float wt = wv[t]/den;
    float mx = wt * sc[w][t*64 + lane];
    float bt = expf(-abn * (float)(T-1-t));
    mixs += fmaxf(aen*mx*bt, 0.f) + mx;
  }
  sco[w][lane] = mixs; sco[w][64+lane] = q;
  __syncthreads();
  float o = 0.f;
  for (int k = 0; k < 128; k++) o += sco[w][k]*sWout[k*64 + lane];
  if (n < N) outp[(size_t)n*H + lane] = tanhf(o);
}

// y = x @ theta, written TRANSPOSED as bf16: xtT[g][f][k], k zero-padded to KP.
__global__ __launch_bounds__(256) void k_xthetaT(const float* __restrict__ x,
                                                 const float* __restrict__ theta,
                                                 int x_per_graph,
                                                 u16* __restrict__ xtT){
  __shared__ float sth[4096];
  __shared__ float sxr[64][64];
  __shared__ float syt[64][65];
  int tid = threadIdx.x, w = tid>>6, lane = tid&63;
  int g = blockIdx.y;
  int r0 = blockIdx.x*64;
  const float* xg = x + (x_per_graph ? (size_t)g*N*64 : (size_t)0);
  for (int k = tid; k < 1024; k += 256) ((float4*)sth)[k] = ((const float4*)theta)[k];
  for (int rr = w; rr < 64; rr += 4){
    int r = r0 + rr;
    sxr[rr][lane] = (r < N) ? xg[(size_t)r*64 + lane] : 0.f;
  }
  __syncthreads();
  for (int rr = w*16; rr < w*16+16; rr++){
    float acc = 0.f;
    for (int d = 0; d < 64; d++) acc = fmaf(sxr[rr][d], sth[d*64 + lane], acc);
    syt[lane][rr] = acc;                 // bank (lane+rr)%32 -> conflict-free
  }
  __syncthreads();
  int col = r0 + lane;
  if (col < KP){
    for (int f = w*16; f < w*16+16; f++)
      xtT[((size_t)g*64 + f)*KP + col] = f2bf(syt[f][lane]);
  }
}

// MFMA conv GEMM: one wave computes rows [m0,m0+16) x 64 cols of
//   C = A_nib[KP x KP-ish] * X  (X given transposed bf16 [64][KP])
// mode 0: out ebufT[g][f][m] bf16 = acc*scale[m]   (pad m -> 0)
// mode 1: out x[g][m][f] fp32 = leaky(acc*scale[m] + bias[f]), m<N only
__global__ __launch_bounds__(64) void k_gemm(const u32* __restrict__ Amat,
                                             const u16* __restrict__ Xt,
                                             int x_per_graph,
                                             const float* __restrict__ scale,
                                             const float* __restrict__ bias,
                                             int mode,
                                             u16* __restrict__ Yt,
                                             float* __restrict__ Yf){
  int g = blockIdx.y;
  int m0 = blockIdx.x * 16;
  int lane = threadIdx.x;
  int mrow = lane & 15, quad = lane >> 4;
  const u32* Arow = Amat + (size_t)g*(GSZB/4) + (size_t)(m0 + mrow)*NWB;
  const u16* Bp = Xt + (x_per_graph ? (size_t)g*64*KP : (size_t)0)
                     + (size_t)mrow*KP + quad*8;
  f32x4 acc[4];
  #pragma unroll
  for (int nt = 0; nt < 4; nt++) acc[nt] = (f32x4){0.f,0.f,0.f,0.f};
  for (int c = 0; c < 33; c++){
    u32 aw = Arow[4*c + quad];           // nibbles k = 32c + quad*8 + j
    bf16x8 af;
    #pragma unroll
    for (int j = 0; j < 8; j++){
      float fv = (float)((aw >> (4*j)) & 0xFu);   // exact small int
      af[j] = (short)f2bf(fv);
    }
    #pragma unroll
    for (int nt = 0; nt < 4; nt++){
      bf16x8 bf = *(const bf16x8*)(Bp + (size_t)nt*16*KP + c*32);
      acc[nt] = __builtin_amdgcn_mfma_f32_16x16x32_bf16(af, bf, acc[nt], 0, 0, 0);
    }
  }
  int mbase = m0 + quad*4;
  float sc_[4];
  #pragma unroll
  for (int r = 0; r < 4; r++){
    int m = mbase + r;
    sc_[r] = (m < N) ? scale[g*N + m] : 0.f;
  }
  if (mode == 0){
    #pragma unroll
    for (int nt = 0; nt < 4; nt++){
      ushort4 o;
      o.x = f2bf(acc[nt][0]*sc_[0]);
      o.y = f2bf(acc[nt][1]*sc_[1]);
      o.z = f2bf(acc[nt][2]*sc_[2]);
      o.w = f2bf(acc[nt][3]*sc_[3]);
      *(ushort4*)(Yt + ((size_t)g*64 + nt*16 + mrow)*KP + mbase) = o;
    }
  } else {
    float bs[4];
    #pragma unroll
    for (int nt = 0; nt < 4; nt++) bs[nt] = bias[nt*16 + mrow];
    #pragma unroll
    for (int r = 0; r < 4; r++){
      int m = mbase + r;
      if (m < N){
        #pragma unroll
        for (int nt = 0; nt < 4; nt++){
          float v = acc[nt][r]*sc_[r] + bs[nt];
          Yf[((size_t)g*N + m)*64 + nt*16 + mrow] = leakyf(v);
        }
      }
    }
  }
}

__global__ __launch_bounds__(256) void k_bmean(const float* __restrict__ x2,
                                               float* __restrict__ bout){
  int k = blockIdx.x, tid = threadIdx.x;
  const float* a = x2 + (size_t)k*N*H;
  const float* c = x2 + (size_t)(k+1)*N*H;
  float s = 0.f;
  for (int i = tid; i < N*H; i += 256) s += c[i] - a[i];
  __shared__ float red[256];
  red[tid] = s; __syncthreads();
  for (int off = 128; off; off >>= 1){ if (tid < off) red[tid] += red[tid+off]; __syncthreads(); }
  if (tid == 0) bout[k] = red[0] / (float)(N*H);
}

__global__ __launch_bounds__(256) void k_zred(const float* __restrict__ x2,
                                              const float* __restrict__ bout,
                                              const float* __restrict__ a_param,
                                              float* __restrict__ zout){
  int k = blockIdx.x, tid = threadIdx.x;
  const float* a = x2 + (size_t)k*N*H;
  const float* c = x2 + (size_t)(k+1)*N*H;
  float bk = bout[k], ap = a_param[k];
  float s = 0.f;
  for (int i = tid; i < N*H; i += 256){
    float sub = c[i] - a[i];
    float U = 1.f/(1.f + ap*(bk - sub));
    s += (U*sub)/U;
  }
  __shared__ float red[256];
  red[tid] = s; __syncthreads();
  for (int off = 128; off; off >>= 1){ if (tid < off) red[tid] += red[tid+off]; __syncthreads(); }
  if (tid == 0) zout[k] = red[0];
}

__global__ __launch_bounds__(64) void k_wattn(const float* __restrict__ z,
                                              const float* __restrict__ w1,
                                              const float* __restrict__ w2,
                                              float* __restrict__ wa){
  __shared__ float sz[TM], sy[64], sv[TM];
  int tid = threadIdx.x;
  if (tid < TM) sz[tid] = z[tid];
  __syncthreads();
  float y = 0.f;
  for (int kk = 0; kk < TM; kk++) y += w1[tid*TM + kk]*sz[kk];
  sy[tid] = leakyf(y);
  __syncthreads();
  if (tid < TM){
    float v = 0.f;
    for (int d = 0; d < 64; d++) v += w2[tid*64 + d]*sy[d];
    sv[tid] = v;
  }
  __syncthreads();
  if (tid == 0){
    float m = sv[0];
    for (int t = 1; t < TM; t++) m = fmaxf(m, sv[t]);
    float e[TM]; float den = 0.f;
    for (int t = 0; t < TM; t++){ e[t] = expf(sv[t]-m); den += e[t]; }
    for (int t = 0; t < TM; t++) wa[t] = e[t]/den;
  }
}

__global__ __launch_bounds__(256) void k_final(const float* __restrict__ x2,
                                               const float* __restrict__ wa,
                                               const float* __restrict__ Wl,
                                               const float* __restrict__ bl,
                                               const int* __restrict__ flag,
                                               void* __restrict__ outv){
  int n = blockIdx.x*256 + threadIdx.x;
  if (n >= N) return;
  float w0 = wa[0], w2v = wa[2];
  float acc = bl[0];
  for (int h = 0; h < 64; h++){
    float xg = x2[(size_t)8*N*H + (size_t)n*64 + h];
    float s0 = x2[(size_t)1*N*H + (size_t)n*64 + h] - x2[(size_t)0*N*H + (size_t)n*64 + h];
    float s2 = x2[(size_t)3*N*H + (size_t)n*64 + h] - x2[(size_t)2*N*H + (size_t)n*64 + h];
    float xx = w0*s0 + w2v*s2;
    acc += xg*Wl[h] + xx*Wl[64 + h];
  }
  float r = leakyf(acc);
  if (*flag) ((float*)outv)[n] = r;
  else       ((__hip_bfloat16*)outv)[n] = __float2bfloat16(r);
}

extern "C" void kernel_launch(void* const* d_in, const int* in_sizes, int n_in,
                              void* d_out, int out_size, void* d_ws, size_t ws_size,
                              hipStream_t stream) {
  const int* hypT = (const int*)d_in[1];
  const int* hyp  = (const int*)d_in[2];

  char* ws = (char*)d_ws;
  float* cv  = (float*)ws;
  int* flag  = (int*)(cv + TOT_CVT);
  u32* cHm   = (u32*)(ws + (size_t)CVT_PAD*4);
  u32* cHmT  = (u32*)(ws + (size_t)CVT_PAD*4 + (size_t)NG*GSZB);
  float* fp  = (float*)(ws + (size_t)CVT_PAD*4 + (size_t)2*NG*GSZB);
  float* Dinv = fp;                 fp += 9236;                 // NG*N padded to x4
  float* Binv = fp;                 fp += 9236;
  float* ctx  = fp;                 fp += (size_t)N*T*H;
  float* last = fp;                 fp += (size_t)N*H;
  float* outp = fp;                 fp += (size_t)N*H;
  float* x1   = fp;                 fp += (size_t)NG*N*H;
  float* x2   = fp;                 fp += (size_t)NG*N*H;
  float* bv   = fp;                 fp += 8;
  float* zv   = fp;                 fp += 8;
  float* wa   = fp;                 fp += 8;
  u16* xtT1   = (u16*)fp;                                       // 64*KP
  u16* xtT2   = xtT1 + (size_t)64*KP;                           // NG*64*KP
  u16* ebufT  = xtT2 + (size_t)NG*64*KP;                        // NG*64*KP

  const float* price  = cv + OFF_PRICE;
  const float* Wih    = cv + OFF_WIH;
  const float* Whh    = cv + OFF_WHH;
  const float* bih    = cv + OFF_BIH;
  const float* bhh    = cv + OFF_BHH;
  const float* Win    = cv + OFF_WIN;
  const float* Wout   = cv + OFF_WOUT;
  const float* ae     = cv + OFF_AE;
  const float* ab     = cv + OFF_AB;
  const float* theta1 = cv + OFF_TH1;
  const float* bias1  = cv + OFF_B1;
  const float* theta2 = cv + OFF_TH2;
  const float* bias2  = cv + OFF_B2;
  const float* w1     = cv + OFF_W1;
  const float* w2     = cv + OFF_W2;
  const float* a_par  = cv + OFF_APAR;
  const float* Wl     = cv + OFF_WL;
  const float* bl     = cv + OFF_BL;

  hipMemsetAsync(cHm, 0, (size_t)2*NG*GSZB, stream);

  k_detect<<<1, 64, 0, stream>>>((const u16*)d_in[3], flag);
  CvtPtrs ps;
  ps.p[0]=d_in[0];  ps.p[1]=d_in[3];  ps.p[2]=d_in[4];  ps.p[3]=d_in[5];
  ps.p[4]=d_in[6];  ps.p[5]=d_in[7];  ps.p[6]=d_in[8];  ps.p[7]=d_in[9];
  ps.p[8]=d_in[10]; ps.p[9]=d_in[11]; ps.p[10]=d_in[12]; ps.p[11]=d_in[13];
  ps.p[12]=d_in[14]; ps.p[13]=d_in[15]; ps.p[14]=d_in[16]; ps.p[15]=d_in[17];
  ps.p[16]=d_in[18]; ps.p[17]=d_in[19];
  k_cvt<<<(TOT_CVT+255)/256, 256, 0, stream>>>(flag, ps, cv);

  k_build<<<dim3((NNZ+255)/256, NG), 256, 0, stream>>>(hypT, hyp, cHm, cHmT);
  k_deg  <<<dim3(N, NG, 2), 64, 0, stream>>>(cHm, cHmT, Dinv, Binv);
  k_gru  <<<(N+3)/4, 256, 0, stream>>>(price, Wih, Whh, bih, bhh, ctx, last);
  k_attn <<<(N+3)/4, 256, 0, stream>>>(ctx, last, Win, Wout, ae, ab, outp);

  // layer 1
  k_xthetaT<<<dim3(17, 1), 256, 0, stream>>>(outp, theta1, 0, xtT1);
  k_gemm<<<dim3(KP/16, NG), 64, 0, stream>>>(cHmT, xtT1, 0, Binv, nullptr, 0, ebufT, nullptr);
  k_gemm<<<dim3(KP/16, NG), 64, 0, stream>>>(cHm, ebufT, 1, Dinv, bias1, 1, nullptr, x1);

  // layer 2
  k_xthetaT<<<dim3(17, NG), 256, 0, stream>>>(x1, theta2, 1, xtT2);
  k_gemm<<<dim3(KP/16, NG), 64, 0, stream>>>(cHmT, xtT2, 1, Binv, nullptr, 0, ebufT, nullptr);
  k_gemm<<<dim3(KP/16, NG), 64, 0, stream>>>(cHm, ebufT, 1, Dinv, bias2, 1, nullptr, x2);

  k_bmean<<<TM, 256, 0, stream>>>(x2, bv);
  k_zred <<<TM, 256, 0, stream>>>(x2, bv, a_par, zv);
  k_wattn<<<1, 64, 0, stream>>>(zv, w1, w2, wa);
  k_final<<<(N+255)/256, 256, 0, stream>>>(x2, wa, Wl, bl, flag, d_out);
}